// Round 1
// 1983.515 us; speedup vs baseline: 1.2253x; 1.2253x over previous
//
#include <hip/hip_runtime.h>
#include <math.h>

// LSTM: B=128, T=256, D=256, H=1024, C=10
// Round 2: attack per-step memory latency (the step GEMM is latency-bound:
// 1 wave/SIMD and a 1-deep pipeline exposed ~200cyc L2 latency x 40 k-tiles).
//   - 512-thread blocks: 8 waves = 4 gates x 2 K-halves (20 k-tiles each).
//     Partial sums combined via LDS (one extra barrier). 2 waves/SIMD TLP.
//   - 4-deep rolling prefetch of A (LDS) and both B streams (global), K-loop
//     fully unrolled so prefetch-slot indices are compile-time constants.
//   - B prologue loads issued before A staging so weight latency overlaps it.
// Everything else (packing, layouts, per-step launches) unchanged.
// Workspace layout (28,311,552 B total):
//   [0)          Wpack  bf16  10,485,760 B
//   [10485760)   xT     bf16  16,777,216 B   ([T][B][D], x transposed+cast)
//   [27262976)   h0     bf16     262,144 B
//   [27525120)   h1     bf16     262,144 B
//   [27787264)   c      fp32     524,288 B

#define BB 128
#define TT 256
#define DD 256
#define HH 1024
#define NKT 40   // 1280 / 32 k-tiles
#define KHT 20   // k-tiles per K-half wave
#define PF 4     // prefetch depth

typedef __bf16 bf16x8 __attribute__((ext_vector_type(8)));
typedef float  f32x4  __attribute__((ext_vector_type(4)));
typedef unsigned short u16;
typedef u16 u16x8 __attribute__((ext_vector_type(8)));

__device__ __forceinline__ u16 f2bf(float f){
  unsigned u = __builtin_bit_cast(unsigned, f);
  u += 0x7fffu + ((u >> 16) & 1u);            // round-to-nearest-even
  return (u16)(u >> 16);
}
__device__ __forceinline__ float bf2f(u16 b){
  unsigned u = ((unsigned)b) << 16;
  return __builtin_bit_cast(float, u);
}

// ---- pack weights into MFMA B-fragment order -------------------------------
// Wpack[ct][kt][lane][j]: ct in [0,256) covers gate-cols [ct*16, ct*16+16)
// (col = gate*1024 + n); element = W[k = kt*32 + (lane>>4)*8 + j][col = ct*16 + (lane&15)]
__global__ void prep_wpack(const float* __restrict__ Wfx, const float* __restrict__ Wix,
                           const float* __restrict__ Wgx, const float* __restrict__ Wox,
                           const float* __restrict__ Wfh, const float* __restrict__ Wih,
                           const float* __restrict__ Wgh, const float* __restrict__ Woh,
                           u16* __restrict__ Wpack){
  int id = blockIdx.x * 256 + threadIdx.x;    // [0, 655360)
  int lane = id & 63;
  int kt = (id >> 6) % NKT;
  int ct = id / (64 * NKT);
  int col = ct * 16 + (lane & 15);
  int g = col >> 10, n = col & 1023;
  int kbase = kt * 32 + (lane >> 4) * 8;
  const float* Wx = (g==0) ? Wfx : (g==1) ? Wix : (g==2) ? Wgx : Wox;
  const float* Wh = (g==0) ? Wfh : (g==1) ? Wih : (g==2) ? Wgh : Woh;
  u16x8 v;
  #pragma unroll
  for (int j = 0; j < 8; ++j){
    int k = kbase + j;
    float f = (k < DD) ? Wx[k * HH + n] : Wh[(k - DD) * HH + n];
    v[j] = f2bf(f);
  }
  *(u16x8*)(Wpack + (size_t)id * 8) = v;      // dst index == id (by construction)
}

// ---- transpose+cast x: xT[t][b][d] = bf16(x[b][t][d]) ----------------------
__global__ void prep_xT(const float* __restrict__ x, u16* __restrict__ xT){
  int id = blockIdx.x * 256 + threadIdx.x;    // [0, 1048576), 8 elems each
  int t = id >> 12;
  int b = (id >> 5) & 127;
  int d0 = (id & 31) * 8;
  const float* src = x + ((size_t)b * TT + t) * DD + d0;
  u16x8 v;
  #pragma unroll
  for (int j = 0; j < 8; ++j) v[j] = f2bf(src[j]);
  *(u16x8*)(xT + (size_t)id * 8) = v;
}

// ---- one LSTM time step: GEMM (bf16 MFMA) + gate activations + state update
__global__ __launch_bounds__(512) void lstm_step(
    const u16* __restrict__ xTt,   // [128][256] bf16 (t-slice of xT)
    const u16* __restrict__ Wpack,
    const u16* __restrict__ hin,   // [128][1024] bf16
    u16* __restrict__ hout,        // [128][1024] bf16
    float* __restrict__ cbuf,      // [128][1024] fp32
    const float* __restrict__ bfv, const float* __restrict__ biv,
    const float* __restrict__ bgv, const float* __restrict__ bov){
  __shared__ u16x8 As4[NKT * 64];  // 40 KB: A tile in fragment order
  __shared__ float gLds[16][132];  // gate exchange (8.25 KB)
  __shared__ float pLds[16][132];  // K-half partial-sum exchange (8.25 KB)
  const int tid = threadIdx.x;
  const int n0 = blockIdx.x * 32;  // hidden-unit tile
  const int m0 = blockIdx.y * 16;  // batch-row tile

  const int w = tid >> 6, lane = tid & 63, cr = lane & 15, q4 = lane >> 4;
  const int g  = w & 3;            // gate
  const int kh = w >> 2;           // K-half: kt in [kh*20, kh*20+20)
  const int ktBeg = kh * KHT;

  // B fragment pointers (global, L2-resident pack); issue prologue loads
  // BEFORE staging so weight latency overlaps the A-staging phase.
  const size_t ct0 = (size_t)(g * 64 + blockIdx.x * 2);  // 2 col-tiles of gate g
  const u16x8* Wp = (const u16x8*)Wpack;
  const u16x8* wq0 = Wp + ct0 * NKT * 64 + lane;
  const u16x8* wq1 = wq0 + NKT * 64;

  u16x8 aP[PF], b0P[PF], b1P[PF];
  #pragma unroll
  for (int i = 0; i < PF; ++i){
    b0P[i] = wq0[(size_t)(ktBeg + i) * 64];
    b1P[i] = wq1[(size_t)(ktBeg + i) * 64];
  }

  // Stage A = [x_t rows | h rows] into LDS in MFMA A-fragment order.
  // chunk ch -> row m = ch/160, k0 = (ch%160)*8 ; frag slot = kt*64 + 16*q + m
  #pragma unroll
  for (int it = 0; it < 5; ++it){
    int ch = tid + it * 512;
    int m = ch / 160;
    int k0 = (ch - m * 160) * 8;
    const u16* src = (k0 < DD) ? (xTt + (m0 + m) * DD + k0)
                               : (hin + (m0 + m) * HH + (k0 - DD));
    u16x8 val = *(const u16x8*)src;
    int kt = k0 >> 5, q = (k0 >> 3) & 3;
    As4[kt * 64 + 16 * q + m] = val;
  }
  __syncthreads();

  #pragma unroll
  for (int i = 0; i < PF; ++i) aP[i] = As4[(ktBeg + i) * 64 + lane];

  f32x4 acc0 = {0.f, 0.f, 0.f, 0.f}, acc1 = {0.f, 0.f, 0.f, 0.f};
  #pragma unroll
  for (int kt = 0; kt < KHT; ++kt){
    const int slot = kt & (PF - 1);          // compile-time (full unroll)
    u16x8 ac = aP[slot], b0 = b0P[slot], b1 = b1P[slot];
    if (kt + PF < KHT){
      aP[slot]  = As4[(ktBeg + kt + PF) * 64 + lane];
      b0P[slot] = wq0[(size_t)(ktBeg + kt + PF) * 64];
      b1P[slot] = wq1[(size_t)(ktBeg + kt + PF) * 64];
    }
    acc0 = __builtin_amdgcn_mfma_f32_16x16x32_bf16(__builtin_bit_cast(bf16x8, ac),
             __builtin_bit_cast(bf16x8, b0), acc0, 0, 0, 0);
    acc1 = __builtin_amdgcn_mfma_f32_16x16x32_bf16(__builtin_bit_cast(bf16x8, ac),
             __builtin_bit_cast(bf16x8, b1), acc1, 0, 0, 0);
  }

  // combine K-halves: kh=1 waves export partials, kh=0 waves add bias + total
  // (C/D layout: col=lane&15, row=q4*4+r)
  if (kh){
    #pragma unroll
    for (int r = 0; r < 4; ++r){
      pLds[q4 * 4 + r][g * 32 + cr]      = acc0[r];
      pLds[q4 * 4 + r][g * 32 + 16 + cr] = acc1[r];
    }
  }
  __syncthreads();
  if (!kh){
    const float* bptr = (g==0) ? bfv : (g==1) ? biv : (g==2) ? bgv : bov;
    float bias0 = bptr[n0 + cr], bias1 = bptr[n0 + 16 + cr];
    #pragma unroll
    for (int r = 0; r < 4; ++r){
      gLds[q4 * 4 + r][g * 32 + cr] =
          acc0[r] + pLds[q4 * 4 + r][g * 32 + cr] + bias0;
      gLds[q4 * 4 + r][g * 32 + 16 + cr] =
          acc1[r] + pLds[q4 * 4 + r][g * 32 + 16 + cr] + bias1;
    }
  }
  __syncthreads();

  // fused LSTM cell update: 512 (row, hidden) units, 1 per thread
  {
    int row = tid >> 5, nn = tid & 31;
    float fp = gLds[row][nn],      ip = gLds[row][32 + nn];
    float gp = gLds[row][64 + nn], op = gLds[row][96 + nn];
    float fs = 1.f / (1.f + expf(-fp));
    float is = 1.f / (1.f + expf(-ip));
    float gs = tanhf(gp);
    float os = 1.f / (1.f + expf(-op));
    int gi = (m0 + row) * HH + n0 + nn;
    float cn = gs * is + cbuf[gi] * fs;
    cbuf[gi] = cn;
    hout[gi] = f2bf(tanhf(cn) * os);
  }
}

// ---- out[b][c] = h_T[b] . Wph[:,c] + bp[c] ---------------------------------
__global__ void final_proj(const u16* __restrict__ h, const float* __restrict__ Wph,
                           const float* __restrict__ bp, float* __restrict__ out){
  __shared__ float red[10][256];
  int b = blockIdx.x, tid = threadIdx.x;
  float p[10];
  #pragma unroll
  for (int c = 0; c < 10; ++c) p[c] = 0.f;
  for (int k = tid; k < HH; k += 256){
    float hv = bf2f(h[b * HH + k]);
    const float* wr = Wph + (size_t)k * 10;
    #pragma unroll
    for (int c = 0; c < 10; ++c) p[c] += hv * wr[c];
  }
  #pragma unroll
  for (int c = 0; c < 10; ++c) red[c][tid] = p[c];
  __syncthreads();
  for (int s = 128; s > 0; s >>= 1){
    if (tid < s){
      #pragma unroll
      for (int c = 0; c < 10; ++c) red[c][tid] += red[c][tid + s];
    }
    __syncthreads();
  }
  if (tid < 10) out[b * 10 + tid] = red[tid][0] + bp[tid];
}

extern "C" void kernel_launch(void* const* d_in, const int* in_sizes, int n_in,
                              void* d_out, int out_size, void* d_ws, size_t ws_size,
                              hipStream_t stream){
  (void)in_sizes; (void)n_in; (void)out_size; (void)ws_size;
  const float* x   = (const float*)d_in[0];
  const float* Wfx = (const float*)d_in[1];
  const float* Wix = (const float*)d_in[2];
  const float* Wgx = (const float*)d_in[3];
  const float* Wox = (const float*)d_in[4];
  const float* Wfh = (const float*)d_in[5];
  const float* Wih = (const float*)d_in[6];
  const float* Wgh = (const float*)d_in[7];
  const float* Woh = (const float*)d_in[8];
  const float* bfv = (const float*)d_in[9];
  const float* biv = (const float*)d_in[10];
  const float* bgv = (const float*)d_in[11];
  const float* bov = (const float*)d_in[12];
  const float* Wph = (const float*)d_in[13];
  const float* bp  = (const float*)d_in[14];

  char* ws = (char*)d_ws;
  u16*  Wpack = (u16*)ws;                    // 10,485,760 B
  u16*  xT    = (u16*)(ws + 10485760);       // 16,777,216 B
  u16*  h0    = (u16*)(ws + 27262976);       //    262,144 B
  u16*  h1    = (u16*)(ws + 27525120);       //    262,144 B
  float* cb   = (float*)(ws + 27787264);     //    524,288 B

  prep_wpack<<<2560, 256, 0, stream>>>(Wfx, Wix, Wgx, Wox, Wfh, Wih, Wgh, Woh, Wpack);
  prep_xT<<<4096, 256, 0, stream>>>(x, xT);
  hipMemsetAsync(h0, 0, 262144, stream);
  hipMemsetAsync(cb, 0, 524288, stream);

  for (int t = 0; t < TT; ++t){
    const u16* hin = (t & 1) ? h1 : h0;
    u16*       hout = (t & 1) ? h0 : h1;
    lstm_step<<<dim3(32, 8), 512, 0, stream>>>(xT + (size_t)t * BB * DD, Wpack,
                                               hin, hout, cb, bfv, biv, bgv, bov);
  }
  // t=255 (odd) wrote h0 -> final hidden state lives in h0
  final_proj<<<128, 256, 0, stream>>>(h0, Wph, bp, (float*)d_out);
}